// Round 5
// baseline (426.462 us; speedup 1.0000x reference)
//
#include <hip/hip_runtime.h>
#include <hip/hip_bf16.h>

#define M_TOK 8192
#define N_OUT 4096
#define K_IN  4096

typedef __attribute__((ext_vector_type(8))) short bf16x8;
typedef __attribute__((ext_vector_type(4))) float f32x4;
typedef unsigned short u16;

// fp32 -> bf16 RNE (finite inputs)
__device__ static inline u16 f2bf(float f) {
    union { float f; unsigned int u; } v; v.f = f;
    unsigned int u = v.u;
    u += 0x7FFFu + ((u >> 16) & 1u);
    return (u16)(u >> 16);
}

__device__ static inline void load_lds16(const void* g, void* l) {
    __builtin_amdgcn_global_load_lds(
        (const __attribute__((address_space(1))) unsigned int*)g,
        (__attribute__((address_space(3))) unsigned int*)l,
        16, 0, 0);
}

// ---------------- fused prep pass (memory-bound, ~HBM roofline) -----------
__global__ void prep_kernel(const float* __restrict__ x,
                            const float* __restrict__ mean,
                            const float* __restrict__ sigma,
                            const float* __restrict__ noise,
                            const int* __restrict__ smult,
                            u16* __restrict__ xb, u16* __restrict__ wb) {
    if (blockIdx.x < 2048) {
        const int n4 = (M_TOK * K_IN) / 4;
        int i = blockIdx.x * blockDim.x + threadIdx.x;
        const int stride = 2048 * 256;
        for (int e = i; e < n4; e += stride) {
            float4 v = reinterpret_cast<const float4*>(x)[e];
            ushort4 o;
            o.x = f2bf(v.x); o.y = f2bf(v.y); o.z = f2bf(v.z); o.w = f2bf(v.w);
            reinterpret_cast<ushort4*>(xb)[e] = o;
        }
    } else {
        const float sm = (float)(*smult);
        const int n4 = (N_OUT * K_IN) / 4;
        int i = (blockIdx.x - 2048) * blockDim.x + threadIdx.x;
        const int stride = 1024 * 256;
        for (int e = i; e < n4; e += stride) {
            float4 m = reinterpret_cast<const float4*>(mean)[e];
            float4 s = reinterpret_cast<const float4*>(sigma)[e];
            float4 z = reinterpret_cast<const float4*>(noise)[e];
            ushort4 o;
            o.x = f2bf(m.x * (1.0f + z.x * fabsf(s.x) * sm));
            o.y = f2bf(m.y * (1.0f + z.y * fabsf(s.y) * sm));
            o.z = f2bf(m.z * (1.0f + z.z * fabsf(s.z) * sm));
            o.w = f2bf(m.w * (1.0f + z.w * fabsf(s.w) * sm));
            reinterpret_cast<ushort4*>(wb)[e] = o;
        }
    }
}

// ------ 256x256 GEMM, 16x16x32 MFMA, read-ahead-1-phase, 1 barrier/phase ---
// C[t][o] = sum_k A[t][k]*B[o][k] + bias[o]; A=[M][K] bf16, B=[N][K] bf16.
// LDS: [buf(2)][A | B][half(2)][8192 elem] = 128 KiB. 16B-slot swizzle
// slot^=(row&7) on global src of global_load_lds + on ds_read (0 conflicts).
// Phase p: {issue reads for phase p+1 ; stage 1 half ; SCHED0 ; QUAD (consumes
// phase p-1 reads via compiler-counted lgkm) ; [drain/gate] ; BAR}.

#define BAR()    __builtin_amdgcn_s_barrier()
#define SCHED0() __builtin_amdgcn_sched_barrier(0)
#define LGKM0() asm volatile("s_waitcnt lgkmcnt(0)" ::: "memory")
#define VMC4()  asm volatile("s_waitcnt vmcnt(4)" ::: "memory")
#define VMC0()  asm volatile("s_waitcnt vmcnt(0)" ::: "memory")

#define DS_A4(AR, MG, AB) \
  _Pragma("unroll") for (int m_ = 0; m_ < 4; ++m_) { \
    AR[m_][0] = *reinterpret_cast<const bf16x8*>((AB) + ((MG)+m_)*1024 + aoff0); \
    AR[m_][1] = *reinterpret_cast<const bf16x8*>((AB) + ((MG)+m_)*1024 + aoff1); }

#define DS_B2(BR, NG, BB) \
  _Pragma("unroll") for (int n_ = 0; n_ < 2; ++n_) { \
    BR[n_][0] = *reinterpret_cast<const bf16x8*>((BB) + ((NG)+n_)*1024 + aoff0); \
    BR[n_][1] = *reinterpret_cast<const bf16x8*>((BB) + ((NG)+n_)*1024 + aoff1); }

#define QUAD(MG, NG, AR, BR) \
  __builtin_amdgcn_s_setprio(1); \
  _Pragma("unroll") for (int m_ = 0; m_ < 4; ++m_) \
  _Pragma("unroll") for (int n_ = 0; n_ < 2; ++n_) { \
    acc[(MG)+m_][(NG)+n_] = __builtin_amdgcn_mfma_f32_16x16x32_bf16( \
        AR[m_][0], BR[n_][0], acc[(MG)+m_][(NG)+n_], 0, 0, 0); \
    acc[(MG)+m_][(NG)+n_] = __builtin_amdgcn_mfma_f32_16x16x32_bf16( \
        AR[m_][1], BR[n_][1], acc[(MG)+m_][(NG)+n_], 0, 0, 0); } \
  __builtin_amdgcn_s_setprio(0);

#define STAGE_A(T, H, BUF) { \
  const u16* g_ = Abase + (size_t)((H)*128 + srow) * K_IN + (T)*64 + sxcol; \
  load_lds16(g_, smem + (BUF)*32768 + (H)*8192 + tid*8); \
  load_lds16(g_ + (size_t)64*K_IN, smem + (BUF)*32768 + (H)*8192 + 4096 + tid*8); }

#define STAGE_B(T, H, BUF) { \
  const u16* g_ = Bbase + (size_t)((H)*128 + srow) * K_IN + (T)*64 + sxcol; \
  load_lds16(g_, smem + (BUF)*32768 + 16384 + (H)*8192 + tid*8); \
  load_lds16(g_ + (size_t)64*K_IN, smem + (BUF)*32768 + 16384 + (H)*8192 + 4096 + tid*8); }

__global__ __launch_bounds__(512, 2)
void gemm_bias_kernel(const u16* __restrict__ A, const u16* __restrict__ B,
                      const float* __restrict__ bias, float* __restrict__ C) {
    __shared__ u16 smem[65536];   // 128 KiB

    const int tid   = threadIdx.x;
    const int lane  = tid & 63;
    const int wid   = tid >> 6;
    const int wm    = wid >> 2;      // 0..1  (M half, 128 rows)
    const int wn    = wid & 3;       // 0..3  (N slice, 64 cols)
    const int la_lo = lane & 15;
    const int la_hi = lane >> 4;

    // T1 v2: per-XCD 2D rectangle (round 3; FETCH 197 MB, keep)
    const int bid = blockIdx.x;
    const int xcd = bid & 7;
    const int c   = bid >> 3;
    const int r   = c >> 5;
    const int s   = c & 31;
    const int bm  = xcd * 4 + (s & 3);
    const int bn  = r * 8 + (s >> 2);
    const int brow = bm * 256;
    const int bcol = bn * 256;

    const u16* Abase = A + (size_t)brow * K_IN;
    const u16* Bbase = B + (size_t)bcol * K_IN;

    // staging swizzle (measured 0 conflicts)
    const int srow  = tid >> 3;
    const int sxcol = ((tid & 7) ^ (srow & 7)) * 8;

    // ds_read swizzled offsets (round-3 pattern, measured 0 conflicts)
    const int xorr  = la_lo & 7;
    const int aoff0 = la_lo * 64 + ((la_hi    ) ^ xorr) * 8;
    const int aoff1 = la_lo * 64 + ((la_hi + 4) ^ xorr) * 8;

    const u16* A0 = smem +         wm * 8192;
    const u16* A1 = smem + 32768 + wm * 8192;
    const u16* B0 = smem +         16384 + (wn >> 1) * 8192 + (wn & 1) * 4096;
    const u16* B1 = smem + 32768 + 16384 + (wn >> 1) * 8192 + (wn & 1) * 4096;

    f32x4 acc[8][4];
    #pragma unroll
    for (int m = 0; m < 8; ++m)
        #pragma unroll
        for (int n = 0; n < 4; ++n)
            acc[m][n] = (f32x4){0.f, 0.f, 0.f, 0.f};

    bf16x8 aE0[4][2], aO0[4][2], aE1[4][2], aO1[4][2];
    bf16x8 bA0[2][2], bB0[2][2], bA1[2][2], bB1[2][2];

    // Prologue: t0 -> b0 (8 loads); B(t1) -> b1 (4 loads, in flight)
    STAGE_B(0, 0, 0); STAGE_B(0, 1, 0);
    STAGE_A(0, 0, 0); STAGE_A(0, 1, 0);
    STAGE_B(1, 0, 1); STAGE_B(1, 1, 1);
    VMC4(); BAR();
    // p0: reads for p1; stage Ah0(t1->b1)
    SCHED0();
    DS_A4(aE0, 0, A0); DS_B2(bA0, 0, B0); STAGE_A(1, 0, 1);
    BAR();

    // Loop: iter i computes tile 2i (QUADs p1-p4, buf0) and 2i+1 (p5-p0', buf1)
    for (int i = 0; i < 31; ++i) {
        const int t1 = 2 * i + 1, t2 = 2 * i + 2, t3 = 2 * i + 3;
        // p1: reads bB0; stage Ah1(t1->b1); QUAD(0,0) b0; drain bB0 pre-BAR
        SCHED0(); DS_B2(bB0, 2, B0); STAGE_A(t1, 1, 1);
        SCHED0(); QUAD(0, 0, aE0, bA0); LGKM0(); BAR();
        // p2: reads aO0; stage Bh0(t2->b0); QUAD(0,2) b0
        SCHED0(); DS_A4(aO0, 4, A0); STAGE_B(t2, 0, 0);
        SCHED0(); QUAD(0, 2, aE0, bB0); BAR();
        // p3: stage Bh1(t2->b0); QUAD(4,2) b0; gate: t1 halves landed
        SCHED0(); STAGE_B(t2, 1, 0);
        SCHED0(); QUAD(4, 2, aO0, bB0); VMC4(); BAR();
        // p4: reads aE1,bA1 (b1 now visible); stage Ah0(t2->b0); QUAD(4,0) b0
        SCHED0(); DS_A4(aE1, 0, A1); DS_B2(bA1, 0, B1); STAGE_A(t2, 0, 0);
        SCHED0(); QUAD(4, 0, aO0, bA0); BAR();
        // p5: reads bB1; stage Ah1(t2->b0); QUAD(0,0) b1; drain bB1 pre-BAR
        SCHED0(); DS_B2(bB1, 2, B1); STAGE_A(t2, 1, 0);
        SCHED0(); QUAD(0, 0, aE1, bA1); LGKM0(); BAR();
        // p6: reads aO1; stage Bh0(t3->b1); QUAD(0,2) b1
        SCHED0(); DS_A4(aO1, 4, A1); STAGE_B(t3, 0, 1);
        SCHED0(); QUAD(0, 2, aE1, bB1); BAR();
        // p7: stage Bh1(t3->b1); QUAD(4,2) b1; gate: t2 halves landed
        SCHED0(); STAGE_B(t3, 1, 1);
        SCHED0(); QUAD(4, 2, aO1, bB1); VMC4(); BAR();
        // p0': reads aE0,bA0 (b0 tile t2 visible); stage Ah0(t3->b1); QUAD(4,0) b1
        SCHED0(); DS_A4(aE0, 0, A0); DS_B2(bA0, 0, B0); STAGE_A(t3, 0, 1);
        SCHED0(); QUAD(4, 0, aO1, bA1); BAR();
    }

    // Peel: b0 = tile 62 (aE0/bA0 pre-read at p0'); b1 = tile 63 (A h1 left)
    SCHED0(); DS_B2(bB0, 2, B0); STAGE_A(63, 1, 1);
    SCHED0(); QUAD(0, 0, aE0, bA0); LGKM0(); BAR();
    SCHED0(); DS_A4(aO0, 4, A0);
    SCHED0(); QUAD(0, 2, aE0, bB0); BAR();
    SCHED0(); QUAD(4, 2, aO0, bB0); VMC0(); BAR();
    SCHED0(); DS_A4(aE1, 0, A1); DS_B2(bA1, 0, B1);
    SCHED0(); QUAD(4, 0, aO0, bA0); BAR();
    SCHED0(); DS_B2(bB1, 2, B1);
    SCHED0(); QUAD(0, 0, aE1, bA1); BAR();
    SCHED0(); DS_A4(aO1, 4, A1);
    SCHED0(); QUAD(0, 2, aE1, bB1); BAR();
    SCHED0(); QUAD(4, 2, aO1, bB1); BAR();
    QUAD(4, 0, aO1, bA1);

    // Epilogue: C/D layout col = lane&15, row = (lane>>4)*4 + r; add bias
    const int crow0 = brow + wm * 128;
    const int ccol0 = bcol + wn * 64;
    #pragma unroll
    for (int n = 0; n < 4; ++n) {
        const int col = ccol0 + n * 16 + la_lo;
        const float bv = bias[col];
        #pragma unroll
        for (int m = 0; m < 8; ++m) {
            #pragma unroll
            for (int rr = 0; rr < 4; ++rr) {
                const int row = crow0 + m * 16 + la_hi * 4 + rr;
                C[(size_t)row * N_OUT + col] = acc[m][n][rr] + bv;
            }
        }
    }
}

extern "C" void kernel_launch(void* const* d_in, const int* in_sizes, int n_in,
                              void* d_out, int out_size, void* d_ws, size_t ws_size,
                              hipStream_t stream) {
    const float* x     = (const float*)d_in[0];
    const float* mean  = (const float*)d_in[1];
    const float* sigma = (const float*)d_in[2];
    const float* bias  = (const float*)d_in[3];
    const float* noise = (const float*)d_in[4];
    const int*   smult = (const int*)d_in[5];
    float* out = (float*)d_out;

    const size_t x_elems = (size_t)M_TOK * K_IN;
    const size_t w_elems = (size_t)N_OUT * K_IN;
    const size_t need = (x_elems + w_elems) * sizeof(u16);
    if (ws_size < need) return;

    u16* xb = (u16*)d_ws;
    u16* wb = xb + x_elems;

    prep_kernel<<<3072, 256, 0, stream>>>(x, mean, sigma, noise, smult, xb, wb);
    gemm_bias_kernel<<<512, 512, 0, stream>>>(xb, wb, bias, out);
}

// Round 6
// 316.565 us; speedup vs baseline: 1.3472x; 1.3472x over previous
//
#include <hip/hip_runtime.h>
#include <hip/hip_bf16.h>

#define M_TOK 8192
#define N_OUT 4096
#define K_IN  4096

typedef __attribute__((ext_vector_type(8))) short bf16x8;
typedef __attribute__((ext_vector_type(4))) float f32x4;
typedef unsigned short u16;

// fp32 -> bf16 RNE (finite inputs)
__device__ static inline u16 f2bf(float f) {
    union { float f; unsigned int u; } v; v.f = f;
    unsigned int u = v.u;
    u += 0x7FFFu + ((u >> 16) & 1u);
    return (u16)(u >> 16);
}

__device__ static inline void load_lds16(const void* g, void* l) {
    __builtin_amdgcn_global_load_lds(
        (const __attribute__((address_space(1))) unsigned int*)g,
        (__attribute__((address_space(3))) unsigned int*)l,
        16, 0, 0);
}

// ---------------- fused prep pass (memory-bound, ~HBM roofline) -----------
__global__ void prep_kernel(const float* __restrict__ x,
                            const float* __restrict__ mean,
                            const float* __restrict__ sigma,
                            const float* __restrict__ noise,
                            const int* __restrict__ smult,
                            u16* __restrict__ xb, u16* __restrict__ wb) {
    if (blockIdx.x < 2048) {
        const int n4 = (M_TOK * K_IN) / 4;
        int i = blockIdx.x * blockDim.x + threadIdx.x;
        const int stride = 2048 * 256;
        for (int e = i; e < n4; e += stride) {
            float4 v = reinterpret_cast<const float4*>(x)[e];
            ushort4 o;
            o.x = f2bf(v.x); o.y = f2bf(v.y); o.z = f2bf(v.z); o.w = f2bf(v.w);
            reinterpret_cast<ushort4*>(xb)[e] = o;
        }
    } else {
        const float sm = (float)(*smult);
        const int n4 = (N_OUT * K_IN) / 4;
        int i = (blockIdx.x - 2048) * blockDim.x + threadIdx.x;
        const int stride = 1024 * 256;
        for (int e = i; e < n4; e += stride) {
            float4 m = reinterpret_cast<const float4*>(mean)[e];
            float4 s = reinterpret_cast<const float4*>(sigma)[e];
            float4 z = reinterpret_cast<const float4*>(noise)[e];
            ushort4 o;
            o.x = f2bf(m.x * (1.0f + z.x * fabsf(s.x) * sm));
            o.y = f2bf(m.y * (1.0f + z.y * fabsf(s.y) * sm));
            o.z = f2bf(m.z * (1.0f + z.z * fabsf(s.z) * sm));
            o.w = f2bf(m.w * (1.0f + z.w * fabsf(s.w) * sm));
            reinterpret_cast<ushort4*>(wb)[e] = o;
        }
    }
}

// ---------------- 256x256 8-phase GEMM (round-3 structure) ----------------
// Single change vs round 3: no lgkmcnt(0) wall after the barrier — the
// compiler's waitcnt pass emits progressive counted lgkm waits per MFMA
// dependency, so the MFMA cluster starts after ~2 reads instead of 12.
// BARM = s_barrier + zero-inst compiler fence (blocks ds_read hoisting
// above the barrier => preserves cross-wave staging visibility).

#define BARM()  { __builtin_amdgcn_s_barrier(); asm volatile("" ::: "memory"); }
#define VMC4()  asm volatile("s_waitcnt vmcnt(4)" ::: "memory")
#define VMC0()  asm volatile("s_waitcnt vmcnt(0)" ::: "memory")

#define DS_A4(AR, MG, AB) \
  _Pragma("unroll") for (int m_ = 0; m_ < 4; ++m_) { \
    AR[m_][0] = *reinterpret_cast<const bf16x8*>((AB) + ((MG)+m_)*1024 + aoff0); \
    AR[m_][1] = *reinterpret_cast<const bf16x8*>((AB) + ((MG)+m_)*1024 + aoff1); }

#define DS_B2(BR, NG, BB) \
  _Pragma("unroll") for (int n_ = 0; n_ < 2; ++n_) { \
    BR[n_][0] = *reinterpret_cast<const bf16x8*>((BB) + ((NG)+n_)*1024 + aoff0); \
    BR[n_][1] = *reinterpret_cast<const bf16x8*>((BB) + ((NG)+n_)*1024 + aoff1); }

#define QUAD(MG, NG, AR, BR) \
  __builtin_amdgcn_s_setprio(1); \
  _Pragma("unroll") for (int m_ = 0; m_ < 4; ++m_) \
  _Pragma("unroll") for (int n_ = 0; n_ < 2; ++n_) { \
    acc[(MG)+m_][(NG)+n_] = __builtin_amdgcn_mfma_f32_16x16x32_bf16( \
        AR[m_][0], BR[n_][0], acc[(MG)+m_][(NG)+n_], 0, 0, 0); \
    acc[(MG)+m_][(NG)+n_] = __builtin_amdgcn_mfma_f32_16x16x32_bf16( \
        AR[m_][1], BR[n_][1], acc[(MG)+m_][(NG)+n_], 0, 0, 0); } \
  __builtin_amdgcn_s_setprio(0);

#define STAGE_A(T, H, BUF) { \
  const u16* g_ = Abase + (size_t)((H)*128 + srow) * K_IN + (T)*64 + sxcol; \
  load_lds16(g_, smem + (BUF)*32768 + (H)*8192 + tid*8); \
  load_lds16(g_ + (size_t)64*K_IN, smem + (BUF)*32768 + (H)*8192 + 4096 + tid*8); }

#define STAGE_B(T, H, BUF) { \
  const u16* g_ = Bbase + (size_t)((H)*128 + srow) * K_IN + (T)*64 + sxcol; \
  load_lds16(g_, smem + (BUF)*32768 + 16384 + (H)*8192 + tid*8); \
  load_lds16(g_ + (size_t)64*K_IN, smem + (BUF)*32768 + 16384 + (H)*8192 + 4096 + tid*8); }

__global__ __launch_bounds__(512, 2)
void gemm_bias_kernel(const u16* __restrict__ A, const u16* __restrict__ B,
                      const float* __restrict__ bias, float* __restrict__ C) {
    __shared__ u16 smem[65536];   // 128 KiB

    const int tid   = threadIdx.x;
    const int lane  = tid & 63;
    const int wid   = tid >> 6;
    const int wm    = wid >> 2;      // 0..1  (M half, 128 rows)
    const int wn    = wid & 3;       // 0..3  (N slice, 64 cols)
    const int la_lo = lane & 15;
    const int la_hi = lane >> 4;

    // T1 v2: per-XCD 2D rectangle (round 3; FETCH 197 MB, keep)
    const int bid = blockIdx.x;
    const int xcd = bid & 7;
    const int c   = bid >> 3;
    const int r   = c >> 5;
    const int s   = c & 31;
    const int bm  = xcd * 4 + (s & 3);
    const int bn  = r * 8 + (s >> 2);
    const int brow = bm * 256;
    const int bcol = bn * 256;

    const u16* Abase = A + (size_t)brow * K_IN;
    const u16* Bbase = B + (size_t)bcol * K_IN;

    // staging swizzle (measured 0 conflicts)
    const int srow  = tid >> 3;
    const int sxcol = ((tid & 7) ^ (srow & 7)) * 8;

    // ds_read swizzled offsets (measured 0 conflicts)
    const int xorr  = la_lo & 7;
    const int aoff0 = la_lo * 64 + ((la_hi    ) ^ xorr) * 8;
    const int aoff1 = la_lo * 64 + ((la_hi + 4) ^ xorr) * 8;

    const u16* A0 = smem +         wm * 8192;
    const u16* A1 = smem + 32768 + wm * 8192;
    const u16* B0 = smem +         16384 + (wn >> 1) * 8192 + (wn & 1) * 4096;
    const u16* B1 = smem + 32768 + 16384 + (wn >> 1) * 8192 + (wn & 1) * 4096;

    f32x4 acc[8][4];
    #pragma unroll
    for (int m = 0; m < 8; ++m)
        #pragma unroll
        for (int n = 0; n < 4; ++n)
            acc[m][n] = (f32x4){0.f, 0.f, 0.f, 0.f};

    bf16x8 aR[4][2], bA[2][2], bB[2][2];

    // Prologue: tile0 fully (8 loads), tile1 B-halves (4 loads)
    STAGE_B(0, 0, 0); STAGE_B(0, 1, 0);
    STAGE_A(0, 0, 0); STAGE_A(0, 1, 0);
    STAGE_B(1, 0, 1); STAGE_B(1, 1, 1);
    VMC4();           // tile0's 8 loads complete; tile1 B may fly
    BARM();

    // Main loop: iteration i computes tiles 2i (buf0) and 2i+1 (buf1),
    // stages Ah(2i+1)@p0/p1, Bh(2i+2)@p2/p3, Ah(2i+2)@p4/p5, Bh(2i+3)@p6/p7.
    for (int i = 0; i < 31; ++i) {
        const int t1 = 2 * i + 1, t2 = 2 * i + 2, t3 = 2 * i + 3;
        // p0
        DS_A4(aR, 0, A0); DS_B2(bA, 0, B0); STAGE_A(t1, 0, 1);
        BARM(); QUAD(0, 0, aR, bA); BARM();
        // p1
        DS_B2(bB, 2, B0); STAGE_A(t1, 1, 1);
        BARM(); QUAD(0, 2, aR, bB); BARM();
        // p2
        DS_A4(aR, 4, A0); STAGE_B(t2, 0, 0);
        BARM(); QUAD(4, 2, aR, bB); BARM();
        // p3  (counted wait: tile 2i+1 fully landed before p4 reads)
        STAGE_B(t2, 1, 0);
        BARM(); QUAD(4, 0, aR, bA); VMC4(); BARM();
        // p4
        DS_A4(aR, 0, A1); DS_B2(bA, 0, B1); STAGE_A(t2, 0, 0);
        BARM(); QUAD(0, 0, aR, bA); BARM();
        // p5
        DS_B2(bB, 2, B1); STAGE_A(t2, 1, 0);
        BARM(); QUAD(0, 2, aR, bB); BARM();
        // p6
        DS_A4(aR, 4, A1); STAGE_B(t3, 0, 1);
        BARM(); QUAD(4, 2, aR, bB); BARM();
        // p7  (counted wait: tile 2i+2 fully landed before next p0 reads)
        STAGE_B(t3, 1, 1);
        BARM(); QUAD(4, 0, aR, bA); VMC4(); BARM();
    }

    // Peeled last pair: tiles 62 (buf0), 63 (buf1); only Ah(63) left to stage
    DS_A4(aR, 0, A0); DS_B2(bA, 0, B0); STAGE_A(63, 0, 1);
    BARM(); QUAD(0, 0, aR, bA); BARM();
    DS_B2(bB, 2, B0); STAGE_A(63, 1, 1);
    BARM(); QUAD(0, 2, aR, bB); BARM();
    DS_A4(aR, 4, A0);
    BARM(); QUAD(4, 2, aR, bB); BARM();
    BARM(); QUAD(4, 0, aR, bA); VMC0(); BARM();
    DS_A4(aR, 0, A1); DS_B2(bA, 0, B1);
    BARM(); QUAD(0, 0, aR, bA); BARM();
    DS_B2(bB, 2, B1);
    BARM(); QUAD(0, 2, aR, bB); BARM();
    DS_A4(aR, 4, A1);
    BARM(); QUAD(4, 2, aR, bB); BARM();
    QUAD(4, 0, aR, bA);

    // Epilogue: C/D layout col = lane&15, row = (lane>>4)*4 + r; add bias
    const int crow0 = brow + wm * 128;
    const int ccol0 = bcol + wn * 64;
    #pragma unroll
    for (int n = 0; n < 4; ++n) {
        const int col = ccol0 + n * 16 + la_lo;
        const float bv = bias[col];
        #pragma unroll
        for (int m = 0; m < 8; ++m) {
            #pragma unroll
            for (int rr = 0; rr < 4; ++rr) {
                const int row = crow0 + m * 16 + la_hi * 4 + rr;
                C[(size_t)row * N_OUT + col] = acc[m][n][rr] + bv;
            }
        }
    }
}

extern "C" void kernel_launch(void* const* d_in, const int* in_sizes, int n_in,
                              void* d_out, int out_size, void* d_ws, size_t ws_size,
                              hipStream_t stream) {
    const float* x     = (const float*)d_in[0];
    const float* mean  = (const float*)d_in[1];
    const float* sigma = (const float*)d_in[2];
    const float* bias  = (const float*)d_in[3];
    const float* noise = (const float*)d_in[4];
    const int*   smult = (const int*)d_in[5];
    float* out = (float*)d_out;

    const size_t x_elems = (size_t)M_TOK * K_IN;
    const size_t w_elems = (size_t)N_OUT * K_IN;
    const size_t need = (x_elems + w_elems) * sizeof(u16);
    if (ws_size < need) return;

    u16* xb = (u16*)d_ws;
    u16* wb = xb + x_elems;

    prep_kernel<<<3072, 256, 0, stream>>>(x, mean, sigma, noise, smult, xb, wb);
    gemm_bias_kernel<<<512, 512, 0, stream>>>(xb, wb, bias, out);
}